// Round 1
// baseline (899.722 us; speedup 1.0000x reference)
//
#include <hip/hip_runtime.h>
#include <cstdint>
#include <cstddef>

// Problem constants
#define NEXP 8
#define NTOK 8192           // B*S = 4*2048
#define DMODEL 1024
#define DFFN 4096
#define CAP 17408           // 16384 assignments + 8*128 padding capacity

typedef __bf16 bf16;
typedef bf16 bf16x8 __attribute__((ext_vector_type(8)));
typedef float f32x4 __attribute__((ext_vector_type(4)));

// ---------------- workspace layout (bytes) ----------------
static constexpr size_t OFF_HDR  = 0;                       // 64 ints: [0..8)cnt [16..24)off [24..32)padded
static constexpr size_t OFF_CNTH = 4096;                    // int[2048*8] per-block assignment hist
static constexpr size_t OFF_AMH  = OFF_CNTH + 65536;        // int[2048*8] per-block argmax hist
static constexpr size_t OFF_PSH  = OFF_AMH + 65536;         // float[2048*8] per-block prob sums
static constexpr size_t OFF_TOKE = OFF_PSH + 65536;         // int[2*NTOK] expert ids
static constexpr size_t OFF_TOKG = OFF_TOKE + 65536;        // float[2*NTOK] gate weights
static constexpr size_t OFF_TOKS = OFF_TOKG + 65536;        // int[2*NTOK] slots
static constexpr size_t OFF_BB   = OFF_TOKS + 65536;        // int[2048*8] per-block slot bases
static constexpr size_t OFF_XG   = OFF_BB + 65536;          // bf16[CAP*DMODEL]
static constexpr size_t OFF_W1B  = OFF_XG  + (size_t)CAP * DMODEL * 2;
static constexpr size_t OFF_W2B  = OFF_W1B + (size_t)NEXP * DFFN * DMODEL * 2;
static constexpr size_t OFF_H    = OFF_W2B + (size_t)NEXP * DMODEL * DFFN * 2;
static constexpr size_t OFF_O    = OFF_H   + (size_t)CAP * DFFN * 2;

// ---------------- small kernels ----------------

__global__ void k_cvt(const float* __restrict__ s, bf16* __restrict__ d, int n8) {
    int i = blockIdx.x * 256 + threadIdx.x;
    if (i >= n8) return;
    const float4* sp = (const float4*)s;
    float4 a = sp[2 * i], b = sp[2 * i + 1];
    bf16x8 pk;
    pk[0] = (bf16)a.x; pk[1] = (bf16)a.y; pk[2] = (bf16)a.z; pk[3] = (bf16)a.w;
    pk[4] = (bf16)b.x; pk[5] = (bf16)b.y; pk[6] = (bf16)b.z; pk[7] = (bf16)b.w;
    ((bf16x8*)d)[i] = pk;
}

// wave-per-token gating: fp32 logits, top-2, full softmax partials, argmax hist
__global__ void k_gate(const float* __restrict__ x, const float* __restrict__ gwt,
                       int* __restrict__ cnth, int* __restrict__ amh, float* __restrict__ psh,
                       int* __restrict__ toke, float* __restrict__ tokg) {
    int tid = threadIdx.x, w = tid >> 6, lane = tid & 63;
    int t = blockIdx.x * 4 + w;
    __shared__ int s_cnt[8]; __shared__ int s_am[8]; __shared__ float s_ps[8];
    if (tid < 8) { s_cnt[tid] = 0; s_am[tid] = 0; s_ps[tid] = 0.f; }
    __syncthreads();
    float acc[8] = {0.f,0.f,0.f,0.f,0.f,0.f,0.f,0.f};
    const float4* xr = (const float4*)(x + (size_t)t * DMODEL);
#pragma unroll
    for (int c = 0; c < 4; c++) {
        float4 xv = xr[c * 64 + lane];
#pragma unroll
        for (int e = 0; e < 8; e++) {
            float4 wv = ((const float4*)(gwt + e * DMODEL))[c * 64 + lane];
            acc[e] = fmaf(xv.x, wv.x, fmaf(xv.y, wv.y, fmaf(xv.z, wv.z, fmaf(xv.w, wv.w, acc[e]))));
        }
    }
#pragma unroll
    for (int o = 32; o; o >>= 1) {
#pragma unroll
        for (int e = 0; e < 8; e++) acc[e] += __shfl_xor(acc[e], o);
    }
    if (lane == 0) {
        int i0 = 0; float v0 = acc[0];
#pragma unroll
        for (int e = 1; e < 8; e++) if (acc[e] > v0) { v0 = acc[e]; i0 = e; }
        int i1 = -1; float v1 = -1e30f;
#pragma unroll
        for (int e = 0; e < 8; e++) if (e != i0 && acc[e] > v1) { v1 = acc[e]; i1 = e; }
        float ex = expf(v1 - v0);
        float g0 = 1.f / (1.f + ex);
        float g1 = ex / (1.f + ex);
        toke[2 * t] = i0; toke[2 * t + 1] = i1;
        tokg[2 * t] = g0; tokg[2 * t + 1] = g1;
        atomicAdd(&s_cnt[i0], 1); atomicAdd(&s_cnt[i1], 1); atomicAdd(&s_am[i0], 1);
        float p[8], sum = 0.f;
#pragma unroll
        for (int e = 0; e < 8; e++) { p[e] = expf(acc[e] - v0); sum += p[e]; }
        float inv = 1.f / sum;
#pragma unroll
        for (int e = 0; e < 8; e++) atomicAdd(&s_ps[e], p[e] * inv);
    }
    __syncthreads();
    if (tid < 8) {
        cnth[blockIdx.x * 8 + tid] = s_cnt[tid];
        amh[blockIdx.x * 8 + tid]  = s_am[tid];
        psh[blockIdx.x * 8 + tid]  = s_ps[tid];
    }
}

// single block: per-gate-block exclusive slot bases (scan), expert offsets, lb_loss.
__global__ void k_offsets(const int* __restrict__ cnth, const int* __restrict__ amh,
                          const float* __restrict__ psh, int* __restrict__ hdr,
                          int* __restrict__ bb, float* __restrict__ lb_out) {
    __shared__ int sc[8][256];
    __shared__ int sa[8][256];
    __shared__ float sp[8][256];
    __shared__ int sOff[8];
    int tid = threadIdx.x;
    int tc[8] = {0,0,0,0,0,0,0,0}, la[8] = {0,0,0,0,0,0,0,0};
    float lp[8] = {0.f,0.f,0.f,0.f,0.f,0.f,0.f,0.f};
    for (int j = 0; j < 8; j++) {
        int b = tid * 8 + j;
#pragma unroll
        for (int e = 0; e < 8; e++) { tc[e] += cnth[b * 8 + e]; la[e] += amh[b * 8 + e]; lp[e] += psh[b * 8 + e]; }
    }
#pragma unroll
    for (int e = 0; e < 8; e++) { sc[e][tid] = tc[e]; sa[e][tid] = la[e]; sp[e][tid] = lp[e]; }
    __syncthreads();
    for (int s = 1; s < 256; s <<= 1) {
        int add[8];
#pragma unroll
        for (int e = 0; e < 8; e++) add[e] = (tid >= s) ? sc[e][tid - s] : 0;
        __syncthreads();
#pragma unroll
        for (int e = 0; e < 8; e++) sc[e][tid] += add[e];
        __syncthreads();
    }
    for (int s = 128; s > 0; s >>= 1) {
        if (tid < s) {
#pragma unroll
            for (int e = 0; e < 8; e++) { sa[e][tid] += sa[e][tid + s]; sp[e][tid] += sp[e][tid + s]; }
        }
        __syncthreads();
    }
    if (tid == 0) {
        int run = 0; float lb = 0.f;
        for (int e = 0; e < 8; e++) {
            int c = sc[e][255];
            hdr[e] = c;
            hdr[16 + e] = run;
            int pad = ((c + 127) >> 7) << 7;
            hdr[24 + e] = pad;
            sOff[e] = run;
            run += pad;
            lb += ((float)sa[e][0] / (float)NTOK) * (sp[e][0] / (float)NTOK);
        }
        lb_out[0] = 8.f * lb;
    }
    __syncthreads();
    int excl[8];
#pragma unroll
    for (int e = 0; e < 8; e++) excl[e] = sOff[e] + sc[e][tid] - tc[e];
    for (int j = 0; j < 8; j++) {
        int b = tid * 8 + j;
#pragma unroll
        for (int e = 0; e < 8; e++) {
            bb[b * 8 + e] = excl[e];
            excl[e] += cnth[b * 8 + e];
        }
    }
}

// wave-per-token: deterministic slot = blockbase + rank-within-block; gather x row (bf16)
__global__ void k_scatter(const float* __restrict__ x, const int* __restrict__ bb,
                          const int* __restrict__ toke, int* __restrict__ toks,
                          bf16* __restrict__ Xg) {
    int tid = threadIdx.x, w = tid >> 6, lane = tid & 63;
    int t = blockIdx.x * 4 + w;
    int a_e = (lane < 8) ? toke[blockIdx.x * 8 + lane] : 0;
    int e0 = __shfl(a_e, 2 * w), e1 = __shfl(a_e, 2 * w + 1);
    int r0 = 0, r1 = 0;
    for (int j = 0; j < 2 * w; j++) {
        int ej = __shfl(a_e, j);
        r0 += (ej == e0);
        r1 += (ej == e1);
    }
    int s0 = bb[blockIdx.x * 8 + e0] + r0;
    int s1 = bb[blockIdx.x * 8 + e1] + r1;
    if (lane == 0) { toks[2 * t] = s0; toks[2 * t + 1] = s1; }
    const float4* xr = (const float4*)(x + (size_t)t * DMODEL);
    bf16* d0 = Xg + (size_t)s0 * DMODEL;
    bf16* d1 = Xg + (size_t)s1 * DMODEL;
#pragma unroll
    for (int c = 0; c < 2; c++) {
        int base = c * 512 + lane * 8;
        float4 u = xr[base >> 2], v = xr[(base >> 2) + 1];
        bf16x8 pk;
        pk[0] = (bf16)u.x; pk[1] = (bf16)u.y; pk[2] = (bf16)u.z; pk[3] = (bf16)u.w;
        pk[4] = (bf16)v.x; pk[5] = (bf16)v.y; pk[6] = (bf16)v.z; pk[7] = (bf16)v.w;
        *(bf16x8*)(d0 + base) = pk;
        *(bf16x8*)(d1 + base) = pk;
    }
}

// zero only the padding rows [cnt[e], padded[e]) of each expert region
__global__ void k_zeropad(const int* __restrict__ hdr, bf16* __restrict__ Xg) {
    int e = blockIdx.x;
    int cnt = hdr[e], off = hdr[16 + e], padded = hdr[24 + e];
    int total = (padded - cnt) * (DMODEL / 8);
    bf16x8* base = (bf16x8*)(Xg + (size_t)(off + cnt) * DMODEL);
    bf16x8 z = {};
    for (int i = threadIdx.x; i < total; i += 256) base[i] = z;
}

// ---------------- deep-pipelined 256x256 grouped MFMA GEMM ----------------
// T1 (XCD swizzle) + T2 (XOR LDS swizzle) + T3/T4 (phase interleave, counted vmcnt,
// ring-4 LDS so vmcnt never drains to 0 in steady state) + T5 (setprio around MFMA).
__device__ __forceinline__ void gll16(const bf16* g, bf16* l) {
    __builtin_amdgcn_global_load_lds((const __attribute__((address_space(1))) unsigned int*)g,
                                     (__attribute__((address_space(3))) unsigned int*)l, 16, 0, 0);
}

// compiler fence + raw HW barrier (NO vmcnt(0) drain, unlike __syncthreads)
__device__ __forceinline__ void wg_bar() {
    asm volatile("" ::: "memory");
    __builtin_amdgcn_s_barrier();
    asm volatile("" ::: "memory");
}

// fast GELU: x * sigmoid(1.5957691*(x + 0.044715 x^3)); |err vs exact| <= ~3e-4
__device__ __forceinline__ float gelu_fast(float x) {
    float x3 = x * x * x;
    float z = fmaf(0.0713548163f, x3, 1.5957691216f * x);
    float s = __builtin_amdgcn_rcpf(1.0f + __expf(-z));
    return x * s;
}

// C[M,ND] = A[M,KD] @ W[ND,KD]^T + bias  (per expert, M = padded token count)
// Tile 256x256, BK=32, 8 waves (2M x 4N), per-wave 128x64 output, acc[8][4] f32x4.
// LDS: ring of 4 K-tile buffers (A 4x16KB @0, B 4x16KB @64KB) = 128 KiB dynamic.
// Stage distance 2 tiles -> steady-state wait is vmcnt(4) (tile t+2's 4 loads stay in flight).
// LDS slot (row, chunk c) holds global k-chunk c ^ (row&3)  (chunk = 8 bf16 = 16B).
template <int KD, int ND, bool GELU_BF16>
__global__ __launch_bounds__(512, 2) void k_gemm256(
    const bf16* __restrict__ Abase, const bf16* __restrict__ Wbase,
    const float* __restrict__ bias, void* __restrict__ Cbase,
    const int* __restrict__ hdr) {
    constexpr int NT = KD / 32;        // K-tiles
    constexpr int GX = ND / 256;       // N-tiles
    constexpr int GYX = GX * 32;
    extern __shared__ char smem[];

    // XCD-aware bijective swizzle: each XCD owns one expert's contiguous tile chunk
    int flat = blockIdx.x + GX * (blockIdx.y + 32 * blockIdx.z);
    constexpr int NPER = GYX * 8 / 8;  // tiles per XCD
    int swz = (flat & 7) * NPER + (flat >> 3);
    int e   = swz / GYX;
    int rem = swz - e * GYX;
    int mt  = rem / GX;
    int nt  = rem - mt * GX;

    int padded = hdr[24 + e];
    if (mt * 256 >= padded) return;
    int mrem = padded - mt * 256; if (mrem > 256) mrem = 256;
    int row0 = hdr[16 + e] + mt * 256;

    const bf16* A = Abase + (size_t)row0 * KD;
    const bf16* W = Wbase + (size_t)e * ND * KD + (size_t)(nt * 256) * KD;

    int tid = threadIdx.x, wid = tid >> 6, lane = tid & 63;
    // staging coords: wave covers 16 rows x 4 chunks per gll16 sweep (128 rows/sweep)
    int srow   = (wid << 4) + (lane >> 2);                 // row within sweep (0..127)
    int schunk = (lane & 3) ^ ((lane >> 2) & 3);           // pre-swizzled source chunk
    // fragment coords
    int wr = wid & 1, wc = wid >> 1;
    int wm = wr << 7, wn = wc << 6;
    int fr = lane & 15, quad = lane >> 4;
    int rchoff = (quad ^ (fr & 3)) << 4;                   // swizzled chunk byte offset

    auto STAGE = [&](int u, int s) {                       // one A sweep + one B sweep
        int b = u & 3;
        int grow  = (s << 7) + srow;
        int garow = (grow < mrem) ? grow : 0;              // clamp M-overhang rows (A only)
        const bf16* ga = A + (size_t)garow * KD + u * 32 + (schunk << 3);
        const bf16* gb = W + (size_t)grow  * KD + u * 32 + (schunk << 3);
        // wave-uniform LDS dest; HW writes lane*16B -> linear rows
        bf16* la = (bf16*)(smem)         + (size_t)b * 8192 + (size_t)(((s << 7) + (wid << 4)) * 32);
        bf16* lb = (bf16*)(smem + 65536) + (size_t)b * 8192 + (size_t)(((s << 7) + (wid << 4)) * 32);
        gll16(ga, la);
        gll16(gb, lb);
    };
    auto LDA = [&](int t, int i) -> bf16x8 {
        const char* base = smem + (t & 3) * 16384;
        return *(const bf16x8*)(base + ((wm + i * 16 + fr) << 6) + rchoff);
    };
    auto LDB = [&](int t, int j) -> bf16x8 {
        const char* base = smem + 65536 + (t & 3) * 16384;
        return *(const bf16x8*)(base + ((wn + j * 16 + fr) << 6) + rchoff);
    };

    // prologue: stage tiles 0 and 1 (8 gll16); land tile 0, keep tile 1 in flight
    STAGE(0, 0); STAGE(0, 1); STAGE(1, 0); STAGE(1, 1);
    asm volatile("s_waitcnt vmcnt(4)" ::: "memory");
    wg_bar();

    f32x4 acc[8][4] = {};
    bf16x8 a4[4], b4[4];

#pragma unroll 1
    for (int t = 0; t < NT; ++t) {
        // ---- phase 0: B frags + A frags 0..3, prefetch half 0 of tile t+2 ----
#pragma unroll
        for (int j = 0; j < 4; j++) b4[j] = LDB(t, j);
#pragma unroll
        for (int i = 0; i < 4; i++) a4[i] = LDA(t, i);
        if (t + 2 < NT) STAGE(t + 2, 0);
        wg_bar();
        __builtin_amdgcn_s_setprio(1);
#pragma unroll
        for (int i = 0; i < 4; i++)
#pragma unroll
            for (int j = 0; j < 4; j++)
                acc[i][j] = __builtin_amdgcn_mfma_f32_16x16x32_bf16(a4[i], b4[j], acc[i][j], 0, 0, 0);
        __builtin_amdgcn_s_setprio(0);
        wg_bar();
        // ---- phase 1: A frags 4..7 (B held in regs), prefetch half 1 of tile t+2 ----
#pragma unroll
        for (int i = 0; i < 4; i++) a4[i] = LDA(t, i + 4);
        if (t + 2 < NT) STAGE(t + 2, 1);
        wg_bar();
        __builtin_amdgcn_s_setprio(1);
#pragma unroll
        for (int i = 0; i < 4; i++)
#pragma unroll
            for (int j = 0; j < 4; j++)
                acc[i + 4][j] = __builtin_amdgcn_mfma_f32_16x16x32_bf16(a4[i], b4[j], acc[i + 4][j], 0, 0, 0);
        __builtin_amdgcn_s_setprio(0);
        // tile boundary: land tile t+1; tile t+2's 4 loads may stay in flight (counted!)
        if (t < NT - 2)      { asm volatile("s_waitcnt vmcnt(4)" ::: "memory"); }
        else if (t < NT - 1) { asm volatile("s_waitcnt vmcnt(0)" ::: "memory"); }
        wg_bar();
    }

    // epilogue: C/D layout col=lane&15, row=quad*4+reg  [verified m89/m91]
#pragma unroll
    for (int j = 0; j < 4; j++) {
        int col = nt * 256 + wn + j * 16 + fr;
        float bv = bias[e * ND + col];
#pragma unroll
        for (int i = 0; i < 8; i++) {
#pragma unroll
            for (int r = 0; r < 4; r++) {
                int rowt = wm + i * 16 + quad * 4 + r;
                if (rowt < mrem) {
                    float v = acc[i][j][r] + bv;
                    size_t idx = (size_t)(row0 + rowt) * ND + col;
                    if (GELU_BF16) {
                        ((bf16*)Cbase)[idx] = (bf16)gelu_fast(v);
                    } else {
                        ((float*)Cbase)[idx] = v;
                    }
                }
            }
        }
    }
}

// out[t] = g0*O[s0] + g1*O[s1]   (O already includes +b2)
__global__ void k_combine(const float* __restrict__ O, const int* __restrict__ toks,
                          const float* __restrict__ tokg, float* __restrict__ out) {
    int t = blockIdx.x;
    int s0 = toks[2 * t], s1 = toks[2 * t + 1];
    float g0 = tokg[2 * t], g1 = tokg[2 * t + 1];
    const float4* o0 = (const float4*)(O + (size_t)s0 * DMODEL);
    const float4* o1 = (const float4*)(O + (size_t)s1 * DMODEL);
    float4* dst = (float4*)(out + (size_t)t * DMODEL);
    int i = threadIdx.x;
    float4 a = o0[i], b = o1[i];
    float4 r;
    r.x = g0 * a.x + g1 * b.x;
    r.y = g0 * a.y + g1 * b.y;
    r.z = g0 * a.z + g1 * b.z;
    r.w = g0 * a.w + g1 * b.w;
    dst[i] = r;
}

// ---------------- launch ----------------
extern "C" void kernel_launch(void* const* d_in, const int* in_sizes, int n_in,
                              void* d_out, int out_size, void* d_ws, size_t ws_size,
                              hipStream_t stream) {
    const float* x   = (const float*)d_in[0];
    const float* gwt = (const float*)d_in[1];
    const float* w1  = (const float*)d_in[2];
    const float* b1  = (const float*)d_in[3];
    const float* w2  = (const float*)d_in[4];
    const float* b2  = (const float*)d_in[5];
    float* out = (float*)d_out;

    char* ws = (char*)d_ws;
    int*   hdr  = (int*)(ws + OFF_HDR);
    int*   cnth = (int*)(ws + OFF_CNTH);
    int*   amh  = (int*)(ws + OFF_AMH);
    float* psh  = (float*)(ws + OFF_PSH);
    int*   toke = (int*)(ws + OFF_TOKE);
    float* tokg = (float*)(ws + OFF_TOKG);
    int*   toks = (int*)(ws + OFF_TOKS);
    int*   bb   = (int*)(ws + OFF_BB);
    bf16*  Xg   = (bf16*)(ws + OFF_XG);
    bf16*  w1b  = (bf16*)(ws + OFF_W1B);
    bf16*  w2b  = (bf16*)(ws + OFF_W2B);
    bf16*  H    = (bf16*)(ws + OFF_H);
    float* O    = (float*)(ws + OFF_O);

    // opt-in to 128 KiB dynamic LDS (once per process)
    static bool s_attr = false;
    if (!s_attr) {
        (void)hipFuncSetAttribute(reinterpret_cast<const void*>(k_gemm256<DMODEL, DFFN, true>),
                                  hipFuncAttributeMaxDynamicSharedMemorySize, 131072);
        (void)hipFuncSetAttribute(reinterpret_cast<const void*>(k_gemm256<DFFN, DMODEL, false>),
                                  hipFuncAttributeMaxDynamicSharedMemorySize, 131072);
        s_attr = true;
    }

    // convert weights to bf16
    k_cvt<<<16384, 256, 0, stream>>>(w1, w1b, 4194304);
    k_cvt<<<16384, 256, 0, stream>>>(w2, w2b, 4194304);
    // gating
    k_gate<<<2048, 256, 0, stream>>>(x, gwt, cnth, amh, psh, toke, tokg);
    // offsets + block bases + lb_loss (written at out[NTOK*DMODEL])
    k_offsets<<<1, 256, 0, stream>>>(cnth, amh, psh, hdr, bb, out + (size_t)NTOK * DMODEL);
    // zero only padding rows of Xg (replaces full 35.7MB zero)
    k_zeropad<<<NEXP, 256, 0, stream>>>(hdr, Xg);
    // scatter tokens (atomic-free)
    k_scatter<<<2048, 256, 0, stream>>>(x, bb, toke, toks, Xg);
    // GEMM1: H = gelu(Xg @ w1^T + b1)   [M x 4096], K=1024
    dim3 g1(DFFN / 256, 32, NEXP);
    k_gemm256<DMODEL, DFFN, true><<<g1, 512, 131072, stream>>>(Xg, w1b, b1, (void*)H, hdr);
    // GEMM2: O = H @ w2^T + b2          [M x 1024], K=4096
    dim3 g2(DMODEL / 256, 32, NEXP);
    k_gemm256<DFFN, DMODEL, false><<<g2, 512, 131072, stream>>>(H, w2b, b2, (void*)O, hdr);
    // combine
    k_combine<<<NTOK, 256, 0, stream>>>(O, toks, tokg, out);
}

// Round 4
// 853.035 us; speedup vs baseline: 1.0547x; 1.0547x over previous
//
#include <hip/hip_runtime.h>
#include <cstdint>
#include <cstddef>

// Problem constants
#define NEXP 8
#define NTOK 8192           // B*S = 4*2048
#define DMODEL 1024
#define DFFN 4096
#define CAP 17408           // 16384 assignments + 8*128 padding capacity

typedef __bf16 bf16;
typedef bf16 bf16x8 __attribute__((ext_vector_type(8)));
typedef float f32x4 __attribute__((ext_vector_type(4)));

// ---------------- workspace layout (bytes) ----------------
static constexpr size_t OFF_HDR  = 0;                       // 64 ints: [0..8)cnt [16..24)off [24..32)padded
static constexpr size_t OFF_CNTH = 4096;                    // int[2048*8] per-block assignment hist
static constexpr size_t OFF_AMH  = OFF_CNTH + 65536;        // int[2048*8] per-block argmax hist
static constexpr size_t OFF_PSH  = OFF_AMH + 65536;         // float[2048*8] per-block prob sums
static constexpr size_t OFF_TOKE = OFF_PSH + 65536;         // int[2*NTOK] expert ids
static constexpr size_t OFF_TOKG = OFF_TOKE + 65536;        // float[2*NTOK] gate weights
static constexpr size_t OFF_TOKS = OFF_TOKG + 65536;        // int[2*NTOK] slots
static constexpr size_t OFF_BB   = OFF_TOKS + 65536;        // int[2048*8] per-block slot bases
static constexpr size_t OFF_XG   = OFF_BB + 65536;          // bf16[CAP*DMODEL]
static constexpr size_t OFF_W1B  = OFF_XG  + (size_t)CAP * DMODEL * 2;
static constexpr size_t OFF_W2B  = OFF_W1B + (size_t)NEXP * DFFN * DMODEL * 2;
static constexpr size_t OFF_H    = OFF_W2B + (size_t)NEXP * DMODEL * DFFN * 2;
static constexpr size_t OFF_O    = OFF_H   + (size_t)CAP * DFFN * 2;

// ---------------- small kernels ----------------

__global__ void k_cvt(const float* __restrict__ s, bf16* __restrict__ d, int n8) {
    int i = blockIdx.x * 256 + threadIdx.x;
    if (i >= n8) return;
    const float4* sp = (const float4*)s;
    float4 a = sp[2 * i], b = sp[2 * i + 1];
    bf16x8 pk;
    pk[0] = (bf16)a.x; pk[1] = (bf16)a.y; pk[2] = (bf16)a.z; pk[3] = (bf16)a.w;
    pk[4] = (bf16)b.x; pk[5] = (bf16)b.y; pk[6] = (bf16)b.z; pk[7] = (bf16)b.w;
    ((bf16x8*)d)[i] = pk;
}

// wave-per-token gating: fp32 logits, top-2, full softmax partials, argmax hist
__global__ void k_gate(const float* __restrict__ x, const float* __restrict__ gwt,
                       int* __restrict__ cnth, int* __restrict__ amh, float* __restrict__ psh,
                       int* __restrict__ toke, float* __restrict__ tokg) {
    int tid = threadIdx.x, w = tid >> 6, lane = tid & 63;
    int t = blockIdx.x * 4 + w;
    __shared__ int s_cnt[8]; __shared__ int s_am[8]; __shared__ float s_ps[8];
    if (tid < 8) { s_cnt[tid] = 0; s_am[tid] = 0; s_ps[tid] = 0.f; }
    __syncthreads();
    float acc[8] = {0.f,0.f,0.f,0.f,0.f,0.f,0.f,0.f};
    const float4* xr = (const float4*)(x + (size_t)t * DMODEL);
#pragma unroll
    for (int c = 0; c < 4; c++) {
        float4 xv = xr[c * 64 + lane];
#pragma unroll
        for (int e = 0; e < 8; e++) {
            float4 wv = ((const float4*)(gwt + e * DMODEL))[c * 64 + lane];
            acc[e] = fmaf(xv.x, wv.x, fmaf(xv.y, wv.y, fmaf(xv.z, wv.z, fmaf(xv.w, wv.w, acc[e]))));
        }
    }
#pragma unroll
    for (int o = 32; o; o >>= 1) {
#pragma unroll
        for (int e = 0; e < 8; e++) acc[e] += __shfl_xor(acc[e], o);
    }
    if (lane == 0) {
        int i0 = 0; float v0 = acc[0];
#pragma unroll
        for (int e = 1; e < 8; e++) if (acc[e] > v0) { v0 = acc[e]; i0 = e; }
        int i1 = -1; float v1 = -1e30f;
#pragma unroll
        for (int e = 0; e < 8; e++) if (e != i0 && acc[e] > v1) { v1 = acc[e]; i1 = e; }
        float ex = expf(v1 - v0);
        float g0 = 1.f / (1.f + ex);
        float g1 = ex / (1.f + ex);
        toke[2 * t] = i0; toke[2 * t + 1] = i1;
        tokg[2 * t] = g0; tokg[2 * t + 1] = g1;
        atomicAdd(&s_cnt[i0], 1); atomicAdd(&s_cnt[i1], 1); atomicAdd(&s_am[i0], 1);
        float p[8], sum = 0.f;
#pragma unroll
        for (int e = 0; e < 8; e++) { p[e] = expf(acc[e] - v0); sum += p[e]; }
        float inv = 1.f / sum;
#pragma unroll
        for (int e = 0; e < 8; e++) atomicAdd(&s_ps[e], p[e] * inv);
    }
    __syncthreads();
    if (tid < 8) {
        cnth[blockIdx.x * 8 + tid] = s_cnt[tid];
        amh[blockIdx.x * 8 + tid]  = s_am[tid];
        psh[blockIdx.x * 8 + tid]  = s_ps[tid];
    }
}

// single block: per-gate-block exclusive slot bases (scan), expert offsets, lb_loss.
__global__ void k_offsets(const int* __restrict__ cnth, const int* __restrict__ amh,
                          const float* __restrict__ psh, int* __restrict__ hdr,
                          int* __restrict__ bb, float* __restrict__ lb_out) {
    __shared__ int sc[8][256];
    __shared__ int sa[8][256];
    __shared__ float sp[8][256];
    __shared__ int sOff[8];
    int tid = threadIdx.x;
    int tc[8] = {0,0,0,0,0,0,0,0}, la[8] = {0,0,0,0,0,0,0,0};
    float lp[8] = {0.f,0.f,0.f,0.f,0.f,0.f,0.f,0.f};
    for (int j = 0; j < 8; j++) {
        int b = tid * 8 + j;
#pragma unroll
        for (int e = 0; e < 8; e++) { tc[e] += cnth[b * 8 + e]; la[e] += amh[b * 8 + e]; lp[e] += psh[b * 8 + e]; }
    }
#pragma unroll
    for (int e = 0; e < 8; e++) { sc[e][tid] = tc[e]; sa[e][tid] = la[e]; sp[e][tid] = lp[e]; }
    __syncthreads();
    for (int s = 1; s < 256; s <<= 1) {
        int add[8];
#pragma unroll
        for (int e = 0; e < 8; e++) add[e] = (tid >= s) ? sc[e][tid - s] : 0;
        __syncthreads();
#pragma unroll
        for (int e = 0; e < 8; e++) sc[e][tid] += add[e];
        __syncthreads();
    }
    for (int s = 128; s > 0; s >>= 1) {
        if (tid < s) {
#pragma unroll
            for (int e = 0; e < 8; e++) { sa[e][tid] += sa[e][tid + s]; sp[e][tid] += sp[e][tid + s]; }
        }
        __syncthreads();
    }
    if (tid == 0) {
        int run = 0; float lb = 0.f;
        for (int e = 0; e < 8; e++) {
            int c = sc[e][255];
            hdr[e] = c;
            hdr[16 + e] = run;
            int pad = ((c + 127) >> 7) << 7;
            hdr[24 + e] = pad;
            sOff[e] = run;
            run += pad;
            lb += ((float)sa[e][0] / (float)NTOK) * (sp[e][0] / (float)NTOK);
        }
        lb_out[0] = 8.f * lb;
    }
    __syncthreads();
    int excl[8];
#pragma unroll
    for (int e = 0; e < 8; e++) excl[e] = sOff[e] + sc[e][tid] - tc[e];
    for (int j = 0; j < 8; j++) {
        int b = tid * 8 + j;
#pragma unroll
        for (int e = 0; e < 8; e++) {
            bb[b * 8 + e] = excl[e];
            excl[e] += cnth[b * 8 + e];
        }
    }
}

// wave-per-token: deterministic slot = blockbase + rank-within-block; gather x row (bf16)
__global__ void k_scatter(const float* __restrict__ x, const int* __restrict__ bb,
                          const int* __restrict__ toke, int* __restrict__ toks,
                          bf16* __restrict__ Xg) {
    int tid = threadIdx.x, w = tid >> 6, lane = tid & 63;
    int t = blockIdx.x * 4 + w;
    int a_e = (lane < 8) ? toke[blockIdx.x * 8 + lane] : 0;
    int e0 = __shfl(a_e, 2 * w), e1 = __shfl(a_e, 2 * w + 1);
    int r0 = 0, r1 = 0;
    for (int j = 0; j < 2 * w; j++) {
        int ej = __shfl(a_e, j);
        r0 += (ej == e0);
        r1 += (ej == e1);
    }
    int s0 = bb[blockIdx.x * 8 + e0] + r0;
    int s1 = bb[blockIdx.x * 8 + e1] + r1;
    if (lane == 0) { toks[2 * t] = s0; toks[2 * t + 1] = s1; }
    const float4* xr = (const float4*)(x + (size_t)t * DMODEL);
    bf16* d0 = Xg + (size_t)s0 * DMODEL;
    bf16* d1 = Xg + (size_t)s1 * DMODEL;
#pragma unroll
    for (int c = 0; c < 2; c++) {
        int base = c * 512 + lane * 8;
        float4 u = xr[base >> 2], v = xr[(base >> 2) + 1];
        bf16x8 pk;
        pk[0] = (bf16)u.x; pk[1] = (bf16)u.y; pk[2] = (bf16)u.z; pk[3] = (bf16)u.w;
        pk[4] = (bf16)v.x; pk[5] = (bf16)v.y; pk[6] = (bf16)v.z; pk[7] = (bf16)v.w;
        *(bf16x8*)(d0 + base) = pk;
        *(bf16x8*)(d1 + base) = pk;
    }
}

// zero only the padding rows [cnt[e], padded[e]) of each expert region
__global__ void k_zeropad(const int* __restrict__ hdr, bf16* __restrict__ Xg) {
    int e = blockIdx.x;
    int cnt = hdr[e], off = hdr[16 + e], padded = hdr[24 + e];
    int total = (padded - cnt) * (DMODEL / 8);
    bf16x8* base = (bf16x8*)(Xg + (size_t)(off + cnt) * DMODEL);
    bf16x8 z = {};
    for (int i = threadIdx.x; i < total; i += 256) base[i] = z;
}

// ---------------- deep-pipelined 256x128 grouped MFMA GEMM, BK=64 ----------------
// T1 XCD swizzle + round-0's MEASURED-conflict-free swizzle (128B rows, 8-chunk XOR)
// + counted vmcnt on a ring-3 LDS (stage distance 2, never drains to 0 in steady
// state) + setprio around MFMA clusters.
__device__ __forceinline__ void gll16(const bf16* g, bf16* l) {
    __builtin_amdgcn_global_load_lds((const __attribute__((address_space(1))) unsigned int*)g,
                                     (__attribute__((address_space(3))) unsigned int*)l, 16, 0, 0);
}

// compiler fence + raw HW barrier (NO vmcnt(0) drain, unlike __syncthreads)
__device__ __forceinline__ void wg_bar() {
    asm volatile("" ::: "memory");
    __builtin_amdgcn_s_barrier();
    asm volatile("" ::: "memory");
}

// fast GELU: x * sigmoid(1.5957691*(x + 0.044715 x^3)); |err vs exact| <= ~3e-4
__device__ __forceinline__ float gelu_fast(float x) {
    float x3 = x * x * x;
    float z = fmaf(0.0713548163f, x3, 1.5957691216f * x);
    float s = __builtin_amdgcn_rcpf(1.0f + __expf(-z));
    return x * s;
}

// C[M,ND] = A[M,KD] @ W[ND,KD]^T + bias  (per expert, M = padded token count)
// Tile 256x128, BK=64, 8 waves (2M x 4N), per-wave 128x32 output, acc[8][2] f32x4.
// LDS ring-3: A slots 3x32KB @0, B slots 3x16KB @96KB = 144 KiB dynamic.
// Row stride 128B (32 banks); LDS (row, c) holds global chunk c ^ (row&7)
// (chunk = 8 bf16 = 16B) -- the round-0 swizzle that measured 0 bank conflicts.
// Stage distance 2 tiles, 3 gll16 per phase; boundary wait = vmcnt(6), never 0.
template <int KD, int ND, bool GELU_BF16>
__global__ __launch_bounds__(512, 2) void k_gemm256(
    const bf16* __restrict__ Abase, const bf16* __restrict__ Wbase,
    const float* __restrict__ bias, void* __restrict__ Cbase,
    const int* __restrict__ hdr) {
    constexpr int NT = KD / 64;        // K-tiles
    constexpr int GX = ND / 128;       // N-tiles
    extern __shared__ char smem[];

    // XCD-aware bijective swizzle: XCD k gets exactly expert k's tiles
    int flat = blockIdx.x + GX * (blockIdx.y + 32 * blockIdx.z);
    int e   = flat & 7;
    int rem = flat >> 3;
    int mt  = rem / GX;
    int nt  = rem - mt * GX;

    int padded = hdr[24 + e];
    if (mt * 256 >= padded) return;
    int mrem = padded - mt * 256; if (mrem > 256) mrem = 256;
    int row0 = hdr[16 + e] + mt * 256;

    const bf16* A = Abase + (size_t)row0 * KD;
    const bf16* W = Wbase + (size_t)e * ND * KD + (size_t)(nt * 128) * KD;

    int tid = threadIdx.x, wid = tid >> 6, lane = tid & 63;
    // staging: each gll16 sweep = 64 lanes x 16B = 8 rows x 128B per wave
    int srow8  = lane >> 3;                       // row within 8-row group
    int schunk = (lane & 7) ^ srow8;              // pre-swizzled source chunk
    // fragment coords
    int wm = (wid & 1) << 7, wn = (wid >> 1) << 5;
    int fr = lane & 15, quad = lane >> 4;
    int swzr = quad ^ (fr & 7);                   // fragment-read chunk xor base

    bf16* As = (bf16*)smem;                       // 3 slots x 16384 elem (32KB)
    bf16* Bs = (bf16*)(smem + 98304);             // 3 slots x  8192 elem (16KB)

    // stage half h (0/1) of K-tile u into slot sl: 2 A sweeps + 1 B sweep = 3 gll16
    auto STAGE_H = [&](int u, int sl, int h) {
        int a0 = (h * 2) * 64 + wid * 8;          // A rows [a0, a0+8)
        int a1 = a0 + 64;                         // A rows [a1, a1+8)
        int b0 = h * 64 + wid * 8;                // B rows [b0, b0+8)
        int gra = a0 + srow8; if (gra >= mrem) gra = 0;   // clamp M-overhang
        int grb = a1 + srow8; if (grb >= mrem) grb = 0;
        gll16(A + (size_t)gra * KD + u * 64 + schunk * 8, As + sl * 16384 + a0 * 64);
        gll16(A + (size_t)grb * KD + u * 64 + schunk * 8, As + sl * 16384 + a1 * 64);
        gll16(W + (size_t)(b0 + srow8) * KD + u * 64 + schunk * 8, Bs + sl * 8192 + b0 * 64);
    };
    auto LDA = [&](int sl, int i, int kx) -> bf16x8 {
        return *(const bf16x8*)((const char*)As + sl * 32768 +
                                ((wm + i * 16 + fr) << 7) + ((swzr ^ (kx << 2)) << 4));
    };
    auto LDB = [&](int sl, int j, int kx) -> bf16x8 {
        return *(const bf16x8*)((const char*)Bs + sl * 16384 +
                                ((wn + j * 16 + fr) << 7) + ((swzr ^ (kx << 2)) << 4));
    };

    // prologue: stage tiles 0 (slot 0) and 1 (slot 1); land tile 0, keep tile 1 in flight
    STAGE_H(0, 0, 0); STAGE_H(0, 0, 1);
    STAGE_H(1, 1, 0); STAGE_H(1, 1, 1);
    asm volatile("s_waitcnt vmcnt(6)" ::: "memory");
    wg_bar();

    f32x4 acc[8][2] = {};
    int sl = 0;

#pragma unroll 1
    for (int t = 0; t < NT; ++t) {
        int sl2 = sl + 2; if (sl2 >= 3) sl2 -= 3;
        bf16x8 a4[4][2], b4[2][2];
        // ---- phase 0: all B frags + A frags 0..3; stage half 0 of tile t+2 ----
#pragma unroll
        for (int j = 0; j < 2; j++) { b4[j][0] = LDB(sl, j, 0); b4[j][1] = LDB(sl, j, 1); }
#pragma unroll
        for (int i = 0; i < 4; i++) { a4[i][0] = LDA(sl, i, 0); a4[i][1] = LDA(sl, i, 1); }
        if (t + 2 < NT) STAGE_H(t + 2, sl2, 0);
        wg_bar();
        __builtin_amdgcn_s_setprio(1);
#pragma unroll
        for (int i = 0; i < 4; i++)
#pragma unroll
            for (int j = 0; j < 2; j++) {
                acc[i][j] = __builtin_amdgcn_mfma_f32_16x16x32_bf16(a4[i][0], b4[j][0], acc[i][j], 0, 0, 0);
                acc[i][j] = __builtin_amdgcn_mfma_f32_16x16x32_bf16(a4[i][1], b4[j][1], acc[i][j], 0, 0, 0);
            }
        __builtin_amdgcn_s_setprio(0);
        wg_bar();
        // ---- phase 1: A frags 4..7 (B held in regs); stage half 1 of tile t+2 ----
#pragma unroll
        for (int i = 0; i < 4; i++) { a4[i][0] = LDA(sl, i + 4, 0); a4[i][1] = LDA(sl, i + 4, 1); }
        if (t + 2 < NT) STAGE_H(t + 2, sl2, 1);
        wg_bar();
        __builtin_amdgcn_s_setprio(1);
#pragma unroll
        for (int i = 0; i < 4; i++)
#pragma unroll
            for (int j = 0; j < 2; j++) {
                acc[i + 4][j] = __builtin_amdgcn_mfma_f32_16x16x32_bf16(a4[i][0], b4[j][0], acc[i + 4][j], 0, 0, 0);
                acc[i + 4][j] = __builtin_amdgcn_mfma_f32_16x16x32_bf16(a4[i][1], b4[j][1], acc[i + 4][j], 0, 0, 0);
            }
        __builtin_amdgcn_s_setprio(0);
        // tile boundary: land tile t+1; tile t+2's 6 loads stay in flight (counted!)
        if (t + 2 < NT)      { asm volatile("s_waitcnt vmcnt(6)" ::: "memory"); }
        else if (t + 1 < NT) { asm volatile("s_waitcnt vmcnt(0)" ::: "memory"); }
        wg_bar();
        sl = sl + 1; if (sl == 3) sl = 0;
    }

    // epilogue: C/D layout col=lane&15, row=quad*4+reg  [verified m89/m91]
#pragma unroll
    for (int j = 0; j < 2; j++) {
        int col = nt * 128 + wn + j * 16 + fr;
        float bv = bias[e * ND + col];
#pragma unroll
        for (int i = 0; i < 8; i++) {
#pragma unroll
            for (int r = 0; r < 4; r++) {
                int rowt = wm + i * 16 + quad * 4 + r;
                if (rowt < mrem) {
                    float v = acc[i][j][r] + bv;
                    size_t idx = (size_t)(row0 + rowt) * ND + col;
                    if (GELU_BF16) {
                        ((bf16*)Cbase)[idx] = (bf16)gelu_fast(v);
                    } else {
                        ((float*)Cbase)[idx] = v;
                    }
                }
            }
        }
    }
}

// out[t] = g0*O[s0] + g1*O[s1]   (O already includes +b2)
__global__ void k_combine(const float* __restrict__ O, const int* __restrict__ toks,
                          const float* __restrict__ tokg, float* __restrict__ out) {
    int t = blockIdx.x;
    int s0 = toks[2 * t], s1 = toks[2 * t + 1];
    float g0 = tokg[2 * t], g1 = tokg[2 * t + 1];
    const float4* o0 = (const float4*)(O + (size_t)s0 * DMODEL);
    const float4* o1 = (const float4*)(O + (size_t)s1 * DMODEL);
    float4* dst = (float4*)(out + (size_t)t * DMODEL);
    int i = threadIdx.x;
    float4 a = o0[i], b = o1[i];
    float4 r;
    r.x = g0 * a.x + g1 * b.x;
    r.y = g0 * a.y + g1 * b.y;
    r.z = g0 * a.z + g1 * b.z;
    r.w = g0 * a.w + g1 * b.w;
    dst[i] = r;
}

// ---------------- launch ----------------
extern "C" void kernel_launch(void* const* d_in, const int* in_sizes, int n_in,
                              void* d_out, int out_size, void* d_ws, size_t ws_size,
                              hipStream_t stream) {
    const float* x   = (const float*)d_in[0];
    const float* gwt = (const float*)d_in[1];
    const float* w1  = (const float*)d_in[2];
    const float* b1  = (const float*)d_in[3];
    const float* w2  = (const float*)d_in[4];
    const float* b2  = (const float*)d_in[5];
    float* out = (float*)d_out;

    char* ws = (char*)d_ws;
    int*   hdr  = (int*)(ws + OFF_HDR);
    int*   cnth = (int*)(ws + OFF_CNTH);
    int*   amh  = (int*)(ws + OFF_AMH);
    float* psh  = (float*)(ws + OFF_PSH);
    int*   toke = (int*)(ws + OFF_TOKE);
    float* tokg = (float*)(ws + OFF_TOKG);
    int*   toks = (int*)(ws + OFF_TOKS);
    int*   bb   = (int*)(ws + OFF_BB);
    bf16*  Xg   = (bf16*)(ws + OFF_XG);
    bf16*  w1b  = (bf16*)(ws + OFF_W1B);
    bf16*  w2b  = (bf16*)(ws + OFF_W2B);
    bf16*  H    = (bf16*)(ws + OFF_H);
    float* O    = (float*)(ws + OFF_O);

    // opt-in to 144 KiB dynamic LDS (once per process)
    static bool s_attr = false;
    if (!s_attr) {
        (void)hipFuncSetAttribute(reinterpret_cast<const void*>(k_gemm256<DMODEL, DFFN, true>),
                                  hipFuncAttributeMaxDynamicSharedMemorySize, 147456);
        (void)hipFuncSetAttribute(reinterpret_cast<const void*>(k_gemm256<DFFN, DMODEL, false>),
                                  hipFuncAttributeMaxDynamicSharedMemorySize, 147456);
        s_attr = true;
    }

    // convert weights to bf16
    k_cvt<<<16384, 256, 0, stream>>>(w1, w1b, 4194304);
    k_cvt<<<16384, 256, 0, stream>>>(w2, w2b, 4194304);
    // gating
    k_gate<<<2048, 256, 0, stream>>>(x, gwt, cnth, amh, psh, toke, tokg);
    // offsets + block bases + lb_loss (written at out[NTOK*DMODEL])
    k_offsets<<<1, 256, 0, stream>>>(cnth, amh, psh, hdr, bb, out + (size_t)NTOK * DMODEL);
    // zero only padding rows of Xg
    k_zeropad<<<NEXP, 256, 0, stream>>>(hdr, Xg);
    // scatter tokens (atomic-free)
    k_scatter<<<2048, 256, 0, stream>>>(x, bb, toke, toks, Xg);
    // GEMM1: H = gelu(Xg @ w1^T + b1)   [M x 4096], K=1024
    dim3 g1(DFFN / 128, 32, NEXP);
    k_gemm256<DMODEL, DFFN, true><<<g1, 512, 147456, stream>>>(Xg, w1b, b1, (void*)H, hdr);
    // GEMM2: O = H @ w2^T + b2          [M x 1024], K=4096
    dim3 g2(DMODEL / 128, 32, NEXP);
    k_gemm256<DFFN, DMODEL, false><<<g2, 512, 147456, stream>>>(H, w2b, b2, (void*)O, hdr);
    // combine
    k_combine<<<NTOK, 256, 0, stream>>>(O, toks, tokg, out);
}